// Round 10
// baseline (247.125 us; speedup 1.0000x reference)
//
#include <hip/hip_runtime.h>
#include <hip/hip_bf16.h>

// B=2, N=2048, E=1024, H=16, D=64 (MQA). out = softmax(causal(QK^T/8)) V @ Wo + bo
//
// Round 10: barrier-free attention.
//   - No LDS staging for Q/K/V: MFMA A/B fragments loaded directly from global
//     (16B/lane dwordx4; K rows and Vt rows are 128B cache lines, L1/L2-hot).
//   - Only P round-trips through per-wave LDS (8 KB/block, in-wave fence only).
//     ZERO __syncthreads in the kernel -> no barrier drains, waves run free.
//   - Softmax math / mask / P layout / grid swizzle: round-9 verbatim (proven).
//   - GEMMs (64x128, Vt fused into QKV epilogue) + prep: round-9 verbatim.

#define NQ 2048
#define BATCH 2
#define HEADS 16
#define HD 64
#define EMB 1024
#define NKV 1152   // 1024 Q cols + 64 K + 64 V

typedef short s16x8 __attribute__((ext_vector_type(8)));
typedef float f32x4 __attribute__((ext_vector_type(4)));
typedef unsigned short ushort_t;

__device__ __forceinline__ ushort_t f2bf(float f) {
    unsigned u = __builtin_bit_cast(unsigned, f);
    u += 0x7fff + ((u >> 16) & 1);          // RNE
    return (ushort_t)(u >> 16);
}

__device__ __forceinline__ void store_out(float* p, float v) { *p = v; }
__device__ __forceinline__ void store_out(ushort_t* p, float v) { *p = f2bf(v); }

// async global->LDS, 16B per lane. LDS dest = wave-uniform base + lane*16.
#define GL16(g, l)                                                                  \
    __builtin_amdgcn_global_load_lds(                                               \
        (const __attribute__((address_space(1))) unsigned int*)(g),                 \
        (__attribute__((address_space(3))) unsigned int*)(l), 16, 0, 0)

// Fused prep: blocks [0,4096): x fp32->bf16. Blocks [4096,6272): 32x32 transpose
// tiles of Wq/Wk/Wv (packed into Wqkv_t, N-major) and Wo -> Wo_t.
__global__ __launch_bounds__(256) void prep(const float* __restrict__ x,
                                            const float* __restrict__ Wq,
                                            const float* __restrict__ Wk,
                                            const float* __restrict__ Wv,
                                            const float* __restrict__ Wo,
                                            ushort_t* __restrict__ xb,
                                            ushort_t* __restrict__ Wqkv_t,
                                            ushort_t* __restrict__ Wo_t) {
    const int bid = blockIdx.x, t = threadIdx.x;
    if (bid < 4096) {
        const int i = bid * 1024 + t * 4;
        const float4 v = *(const float4*)&x[i];
        ushort_t o[4] = {f2bf(v.x), f2bf(v.y), f2bf(v.z), f2bf(v.w)};
        *(uint2*)&xb[i] = *(uint2*)o;
        return;
    }
    int tb = bid - 4096;
    const float* src; ushort_t* dst; int N, n0, k0;
    if (tb < 1024)      { src = Wq; N = 1024; dst = Wqkv_t;
                          n0 = (tb & 31) * 32; k0 = (tb >> 5) * 32; }
    else if (tb < 1088) { tb -= 1024; src = Wk; N = 64; dst = Wqkv_t + (size_t)1024 * EMB;
                          n0 = (tb & 1) * 32; k0 = (tb >> 1) * 32; }
    else if (tb < 1152) { tb -= 1088; src = Wv; N = 64; dst = Wqkv_t + (size_t)1088 * EMB;
                          n0 = (tb & 1) * 32; k0 = (tb >> 1) * 32; }
    else                { tb -= 1152; src = Wo; N = 1024; dst = Wo_t;
                          n0 = (tb & 31) * 32; k0 = (tb >> 5) * 32; }
    __shared__ float tile[32][33];
    const int tx = t & 31, ty = t >> 5;
#pragma unroll
    for (int i = 0; i < 32; i += 8)
        tile[ty + i][tx] = src[(size_t)(k0 + ty + i) * N + n0 + tx];
    __syncthreads();
#pragma unroll
    for (int i = 0; i < 32; i += 8)
        dst[(size_t)(n0 + ty + i) * EMB + k0 + tx] = f2bf(tile[tx][ty + i]);
}

// bf16 MFMA GEMM: C(M,N) = A(M,K) @ Bt(N,K)^T [+ bias]. 64x128 tile, BK=32.
// WRITE_VT: cols >= 1088 additionally write transposed bf16 to Vt[b][d][n].
template<bool HAS_BIAS, bool WRITE_VT, typename OutT>
__global__ __launch_bounds__(256) void gemm_bf16(const ushort_t* __restrict__ A,
                                                 const ushort_t* __restrict__ Bt,
                                                 const float* __restrict__ bias,
                                                 OutT* __restrict__ C,
                                                 ushort_t* __restrict__ Vt,
                                                 int M, int N, int K) {
    __shared__ __align__(16) ushort_t Al[64 * 32];
    __shared__ __align__(16) ushort_t Bl[128 * 32];
    const int t = threadIdx.x;
    const int w = t >> 6, lane = t & 63, quad = lane >> 4, ln = lane & 15;
    const int row0 = blockIdx.y * 64, col0 = blockIdx.x * 128;

    const int rA = t >> 2;
    const int lcA = (t & 3) ^ ((rA >> 1) & 3);
    const int rB1 = 64 + rA;
    const ushort_t* ga  = A  + (size_t)(row0 + rA) * K + lcA * 8;
    const ushort_t* gb0 = Bt + (size_t)(col0 + rA) * K + lcA * 8;
    const ushort_t* gb1 = Bt + (size_t)(col0 + rB1) * K + lcA * 8;
    ushort_t* lA  = Al + w * 512;
    ushort_t* lB0 = Bl + w * 512;
    ushort_t* lB1 = Bl + 2048 + w * 512;

    f32x4 acc[4][2] = {};
    const int sw = (ln >> 1) & 3;
    for (int k0 = 0; k0 < K; k0 += 32) {
        GL16(ga, lA); GL16(gb0, lB0); GL16(gb1, lB1);
        ga += 32; gb0 += 32; gb1 += 32;
        __syncthreads();

        s16x8 af[4], bf[2];
#pragma unroll
        for (int mt = 0; mt < 4; ++mt)
            af[mt] = *(const s16x8*)&Al[(mt * 16 + ln) * 32 + ((quad ^ sw) * 8)];
#pragma unroll
        for (int nt = 0; nt < 2; ++nt)
            bf[nt] = *(const s16x8*)&Bl[(w * 32 + nt * 16 + ln) * 32 + ((quad ^ sw) * 8)];
#pragma unroll
        for (int mt = 0; mt < 4; ++mt)
#pragma unroll
            for (int nt = 0; nt < 2; ++nt)
                acc[mt][nt] = __builtin_amdgcn_mfma_f32_16x16x32_bf16(
                    af[mt], bf[nt], acc[mt][nt], 0, 0, 0);
        __syncthreads();
    }

#pragma unroll
    for (int nt = 0; nt < 2; ++nt) {
        const int col = col0 + w * 32 + nt * 16 + ln;
        const float bv = HAS_BIAS ? bias[col] : 0.f;
#pragma unroll
        for (int mt = 0; mt < 4; ++mt) {
#pragma unroll
            for (int r = 0; r < 4; ++r) {
                const int row = row0 + mt * 16 + quad * 4 + r;
                store_out(&C[(size_t)row * N + col], acc[mt][nt][r] + bv);
            }
            if (WRITE_VT && col >= 1088) {
                const int d = col - 1088;
                const int n = row0 + mt * 16 + quad * 4;   // 4 consecutive rows
                const int bb = n >> 11, nn = n & 2047;
                ushort_t tmp[4] = {f2bf(acc[mt][nt][0]), f2bf(acc[mt][nt][1]),
                                   f2bf(acc[mt][nt][2]), f2bf(acc[mt][nt][3])};
                *(uint2*)&Vt[((size_t)bb * 64 + d) * NQ + nn] = *(uint2*)tmp;
            }
        }
    }
}

// P LDS frag read: [row][chunk] with physical chunk = logical ^ (row&7).
__device__ __forceinline__ s16x8 frag(const ushort_t* lds, int row, int lc) {
    const int phys = lc ^ (row & 7);
    return *(const s16x8*)&lds[row * 64 + phys * 8];
}

// Barrier-free flash attention. Grid = 1024 blocks, round-9 qt swizzle (the 4
// blocks co-resident per CU sum to 66 iters). Each wave owns 16 q-rows; Q/K/Vt
// fragments loaded straight from global in MFMA layout (K row = one 128B line,
// Vt row-segment = one 128B line; L1 shares across the block's 4 waves).
// Only P goes through LDS (per-wave rows, in-wave lgkmcnt fence). No barriers.
__global__ __launch_bounds__(256, 4) void attn_mfma(const ushort_t* __restrict__ QKV,
                                                    const ushort_t* __restrict__ Vt,
                                                    ushort_t* __restrict__ Z) {
    const int bid = blockIdx.x;
    const int b = (bid >> 4) & 1, h = bid & 15;
    const int i = bid >> 5, k = i >> 3, j = i & 7;
    const int qt = (k == 0) ? 2 * j : (k == 1) ? 31 - 2 * j
                 : (k == 2) ? 2 * j + 1 : 30 - 2 * j;
    const int t = threadIdx.x;
    const int w = t >> 6, lane = t & 63, quad = lane >> 4, ln = lane & 15;

    __shared__ __align__(16) ushort_t Ps[4 * 16 * 64];     // 8 KB, per-wave 2 KB

    const ushort_t* Kg = QKV + (size_t)b * NQ * NKV + 1024;   // [key][d], row=NKV
    const ushort_t* Vg = Vt + (size_t)b * 64 * NQ;            // [d][key], row=NQ
    ushort_t* Pw = Ps + w * 1024;

    // Q A-frags straight from global: row = qtile + w*16 + ln, d = frag*32 + quad*8
    const ushort_t* qrow =
        QKV + (size_t)(b * NQ + qt * 64 + w * 16 + ln) * NKV + h * HD;
    const s16x8 aQ0 = *(const s16x8*)(qrow + quad * 8);
    const s16x8 aQ1 = *(const s16x8*)(qrow + 32 + quad * 8);

    f32x4 o[4];
#pragma unroll
    for (int ii = 0; ii < 4; ++ii) o[ii] = f32x4{0.f, 0.f, 0.f, 0.f};
    float mrow[4], lrow[4];
#pragma unroll
    for (int r = 0; r < 4; ++r) { mrow[r] = -1e30f; lrow[r] = 0.f; }

#pragma unroll 1
    for (int jt = 0; jt <= qt; ++jt) {
        // K B-frags: B[k=d][n=key] -> lane reads K[jt*64 + nt*16 + ln][half*32 + quad*8]
        const ushort_t* kb = Kg + (size_t)(jt * 64 + ln) * NKV + quad * 8;
        s16x8 kf0[4], kf1[4];
#pragma unroll
        for (int nt = 0; nt < 4; ++nt) {
            kf0[nt] = *(const s16x8*)(kb + (size_t)(nt * 16) * NKV);
            kf1[nt] = *(const s16x8*)(kb + (size_t)(nt * 16) * NKV + 32);
        }

        // S = Q K^T
        f32x4 s[4];
#pragma unroll
        for (int nt = 0; nt < 4; ++nt) {
            f32x4 acc = f32x4{0.f, 0.f, 0.f, 0.f};
            acc = __builtin_amdgcn_mfma_f32_16x16x32_bf16(aQ0, kf0[nt], acc, 0, 0, 0);
            acc = __builtin_amdgcn_mfma_f32_16x16x32_bf16(aQ1, kf1[nt], acc, 0, 0, 0);
            s[nt] = acc;
        }

        // V B-frags issued now -> ~200cy L2 latency hides under the softmax chain.
        const ushort_t* vb = Vg + (size_t)ln * NQ + jt * 64 + quad * 8;
        s16x8 vf0[4], vf1[4];
#pragma unroll
        for (int ntd = 0; ntd < 4; ++ntd) {
            vf0[ntd] = *(const s16x8*)(vb + (size_t)(ntd * 16) * NQ);
            vf1[ntd] = *(const s16x8*)(vb + (size_t)(ntd * 16) * NQ + 32);
        }

        // scale + causal mask + online softmax (rows w*16 + quad*4 + r) [r9 verbatim]
        const bool diag = (jt == qt);
        float rmax[4];
#pragma unroll
        for (int r = 0; r < 4; ++r) rmax[r] = -1e30f;
#pragma unroll
        for (int nt = 0; nt < 4; ++nt)
#pragma unroll
            for (int r = 0; r < 4; ++r) {
                float v = s[nt][r] * 0.125f;
                if (diag && (nt * 16 + ln) > (w * 16 + quad * 4 + r)) v = -1e30f;
                s[nt][r] = v;
                rmax[r] = fmaxf(rmax[r], v);
            }
#pragma unroll
        for (int r = 0; r < 4; ++r) {
            rmax[r] = fmaxf(rmax[r], __shfl_xor(rmax[r], 1));
            rmax[r] = fmaxf(rmax[r], __shfl_xor(rmax[r], 2));
            rmax[r] = fmaxf(rmax[r], __shfl_xor(rmax[r], 4));
            rmax[r] = fmaxf(rmax[r], __shfl_xor(rmax[r], 8));
        }
        float alpha[4], rsum[4];
#pragma unroll
        for (int r = 0; r < 4; ++r) {
            const float mnew = fmaxf(mrow[r], rmax[r]);
            alpha[r] = __expf(mrow[r] - mnew);
            mrow[r] = mnew;
            rsum[r] = 0.f;
        }
#pragma unroll
        for (int nt = 0; nt < 4; ++nt)
#pragma unroll
            for (int r = 0; r < 4; ++r) {
                const float pv = __expf(s[nt][r] - mrow[r]);
                s[nt][r] = pv;
                rsum[r] += pv;
            }
#pragma unroll
        for (int r = 0; r < 4; ++r) {
            rsum[r] += __shfl_xor(rsum[r], 1);
            rsum[r] += __shfl_xor(rsum[r], 2);
            rsum[r] += __shfl_xor(rsum[r], 4);
            rsum[r] += __shfl_xor(rsum[r], 8);
            lrow[r] = lrow[r] * alpha[r] + rsum[r];
        }
#pragma unroll
        for (int ntd = 0; ntd < 4; ++ntd)
#pragma unroll
            for (int r = 0; r < 4; ++r) o[ntd][r] *= alpha[r];

        // P -> per-wave LDS rows (XOR-swizzled, r9 layout), re-read in A-layout.
#pragma unroll
        for (int nt = 0; nt < 4; ++nt)
#pragma unroll
            for (int r = 0; r < 4; ++r) {
                const int prow = quad * 4 + r;
                const int pc = (nt * 2 + (ln >> 3)) ^ (prow & 7);
                Pw[prow * 64 + pc * 8 + (ln & 7)] = f2bf(s[nt][r]);
            }
        asm volatile("s_waitcnt lgkmcnt(0)" ::: "memory");

        const s16x8 aP0 = frag(Pw, ln, quad);
        const s16x8 aP1 = frag(Pw, ln, 4 + quad);
#pragma unroll
        for (int ntd = 0; ntd < 4; ++ntd) {
            o[ntd] = __builtin_amdgcn_mfma_f32_16x16x32_bf16(aP0, vf0[ntd], o[ntd], 0, 0, 0);
            o[ntd] = __builtin_amdgcn_mfma_f32_16x16x32_bf16(aP1, vf1[ntd], o[ntd], 0, 0, 0);
        }
    }

    // epilogue: normalize + store Z (bf16)
    float invl[4];
#pragma unroll
    for (int r = 0; r < 4; ++r) invl[r] = 1.f / lrow[r];
#pragma unroll
    for (int ntd = 0; ntd < 4; ++ntd)
#pragma unroll
        for (int r = 0; r < 4; ++r) {
            const size_t row = (size_t)(b * NQ + qt * 64 + w * 16 + quad * 4 + r);
            Z[row * EMB + h * HD + ntd * 16 + ln] = f2bf(o[ntd][r] * invl[r]);
        }
}

extern "C" void kernel_launch(void* const* d_in, const int* in_sizes, int n_in,
                              void* d_out, int out_size, void* d_ws, size_t ws_size,
                              hipStream_t stream) {
    const float* x  = (const float*)d_in[0];
    const float* Wq = (const float*)d_in[1];
    const float* Wk = (const float*)d_in[2];
    const float* Wv = (const float*)d_in[3];
    const float* Wo = (const float*)d_in[4];
    const float* bo = (const float*)d_in[5];
    float* out = (float*)d_out;

    const int M = BATCH * NQ;                                   // 4096
    char* ws = (char*)d_ws;
    ushort_t* xb     = (ushort_t*)ws;                                      // 8 MB
    ushort_t* Wqkv_t = (ushort_t*)(ws + (size_t)8  * 1024 * 1024);         // 2.25 MB
    ushort_t* Wo_t   = (ushort_t*)(ws + (size_t)11 * 1024 * 1024);         // 2 MB
    ushort_t* QKV    = (ushort_t*)(ws + (size_t)13 * 1024 * 1024);         // 9.22 MB
    ushort_t* Vt     = (ushort_t*)(ws + (size_t)23 * 1024 * 1024);         // 0.5 MB
    ushort_t* Zb     = (ushort_t*)(ws + (size_t)24 * 1024 * 1024);         // 8 MB

    dim3 blk(256);
    prep<<<dim3(6272), blk, 0, stream>>>(x, Wq, Wk, Wv, Wo, xb, Wqkv_t, Wo_t);
    gemm_bf16<false, true, ushort_t><<<dim3(NKV / 128, M / 64), blk, 0, stream>>>(
        xb, Wqkv_t, nullptr, QKV, Vt, M, NKV, EMB);
    attn_mfma<<<dim3(1024), blk, 0, stream>>>(QKV, Vt, Zb);
    gemm_bf16<true, false, float><<<dim3(EMB / 128, M / 64), blk, 0, stream>>>(
        Zb, Wo_t, bo, out, nullptr, M, EMB, EMB);
}